// Round 2
// baseline (244.129 us; speedup 1.0000x reference)
//
#include <hip/hip_runtime.h>
#include <math.h>

// Problem constants (from reference): features [B,H,W,D,F] float32
#define BB 16
#define HH 128
#define WW 128
#define DD 8
#define FF 16

// Fused: rotate(40deg, NN, expand=False, fill=0) -> roll((5,-7),(H,W)) -> flip(W,D)
// out[b,h,w,d,f] = valid(i,j) ? feat[b, si(i,j), sj(i,j), 7-d, f] : 0
//   i = (h - 5) mod H ; j = (134 - w) mod W
//
// R2 structure: the gather's 512B reads are scattered along rotated diagonals.
// Cold in HBM they run at ~1.2 TB/s (R1: 222 us). Input (134 MB) fits in the
// 256 MiB Infinity Cache, so kernel 1 streams the input contiguously to warm
// the MALL, then kernel 2's scattered reads hit L3 instead of HBM pages.

__global__ __launch_bounds__(256) void prefetch_kernel(const float4* __restrict__ in,
                                                       float* __restrict__ ws) {
    // 4096 blocks * 256 threads * 8 float4 = 8388608 float4 = 134217728 B
    int tid = blockIdx.x * blockDim.x + threadIdx.x;
    const int stride = 4096 * 256;
    float s = 0.f;
    #pragma unroll
    for (int k = 0; k < 8; ++k) {
        float4 v = in[tid + k * stride];
        s += v.x + v.y + v.z + v.w;
    }
    // Never-true data-dependent store: keeps the loads alive, no real traffic.
    if (s == 1.0e38f) ws[0] = s;
}

__global__ __launch_bounds__(256) void aug_kernel(const float4* __restrict__ in,
                                                  float4* __restrict__ out,
                                                  int n_vec4) {
    int tid = blockIdx.x * blockDim.x + threadIdx.x;  // one float4 of output
    if (tid >= n_vec4) return;

    // decompose: tid = ((((b*H + h)*W + w)*D + d)*4 + f4)
    int t  = tid;
    int f4 = t & 3;   t >>= 2;
    int d  = t & 7;   t >>= 3;
    int w  = t & 127; t >>= 7;
    int h  = t & 127; t >>= 7;
    int b  = t;       // 0..15

    // compose roll + W-flip into rotated-space coords
    int i = (h + 123) & 127;   // (h - 5) mod 128
    int j = (134 - w) & 127;

    // inverse-rotation NN map (f64, exact; rint = half-to-even like np.round)
    const double c = 0.76604444311897803;  // cos(40 deg)
    const double s = 0.64278760968653933;  // sin(40 deg)
    const double cy = 63.5, cx = 63.5;
    double di = (double)i - cy;
    double dj = (double)j - cx;
    double src_i = c * di + s * dj + cy;
    double src_j = -s * di + c * dj + cx;
    int si = (int)rint(src_i);
    int sj = (int)rint(src_j);
    bool valid = (si >= 0) & (si < HH) & (sj >= 0) & (sj < WW);

    float4 v = make_float4(0.f, 0.f, 0.f, 0.f);
    if (valid) {
        int dd = 7 - d;  // D-flip
        long long src = ((((long long)b * HH + si) * WW + sj) * DD + dd) * 4 + f4;
        v = in[src];
    }
    out[tid] = v;
}

extern "C" void kernel_launch(void* const* d_in, const int* in_sizes, int n_in,
                              void* d_out, int out_size, void* d_ws, size_t ws_size,
                              hipStream_t stream) {
    const float4* in = (const float4*)d_in[0];
    float4* out = (float4*)d_out;

    // Kernel 1: warm the Infinity Cache with a contiguous stream of the input.
    prefetch_kernel<<<4096, 256, 0, stream>>>(in, (float*)d_ws);

    // Kernel 2: the fused gather (reads now hit MALL, writes stream to HBM).
    int n_vec4 = out_size / 4;  // 8388608
    int block = 256;
    int grid = (n_vec4 + block - 1) / block;  // 32768
    aug_kernel<<<grid, block, 0, stream>>>(in, out, n_vec4);
}

// Round 3
// 230.548 us; speedup vs baseline: 1.0589x; 1.0589x over previous
//
#include <hip/hip_runtime.h>
#include <math.h>

// features [B,H,W,D,F] = [16,128,128,8,16] float32
// out[b,h,w,d,f] = valid(i,j) ? in[b, si(i,j), sj(i,j), 7-d, f] : 0
//   i = (h - 5) mod 128 ; j = (134 - w) mod 128
//   (si,sj) = round(inverse-rotation 40deg about (63.5,63.5)), f64 exact.
//
// R3: 32x32 (h,w) tiles per block. A tile's source footprint is a rotated
// 32x32 square -> per source row ~23 CONTIGUOUS 512B blocks (~11.6 KB runs)
// instead of isolated 512B granules 42 KB apart (R1/R2 diagonal walk).
// Writes: one contiguous 16 KB output row per block-iteration, nontemporal
// (output is write-once; don't evict the 1.3x-reused source from L2/MALL).

typedef float f32x4 __attribute__((ext_vector_type(4)));

#define HH 128
#define WW 128

__global__ __launch_bounds__(1024) void aug_tiled(const f32x4* __restrict__ in,
                                                  f32x4* __restrict__ out) {
    // grid: 256 = b(16) x tileH(4) x tileW(4); block: 1024 threads
    int blk = blockIdx.x;
    int tw0 = (blk & 3) << 5;          // tile origin in w
    int th0 = ((blk >> 2) & 3) << 5;   // tile origin in h
    int b   = blk >> 4;

    int t  = threadIdx.x;
    int f4 = t & 3;          // float4 index within F=16
    int d  = (t >> 2) & 7;
    int wp = t >> 5;         // 0..31: w' within tile
    int dd = 7 - d;          // D-flip

    int w = tw0 + wp;
    int j = (134 - w) & 127; // roll(-7) + W-flip composed

    const double c = 0.76604444311897803;  // cos(40 deg)
    const double s = 0.64278760968653933;  // sin(40 deg)
    double dj = (double)j - 63.5;
    double sjc = c * dj + 63.5;   // j-dependent parts hoisted
    double sic = s * dj + 63.5;

    long long base_b = (long long)b * (HH * WW * 8 * 4);  // float4 units

    #pragma unroll 4
    for (int hp = 0; hp < 32; ++hp) {
        int h = th0 + hp;
        int i = (h + 123) & 127;  // roll(5) on H
        double di = (double)i - 63.5;
        int si = (int)rint(c * di + sic);
        int sj = (int)rint(-s * di + sjc);
        bool valid = (si >= 0) & (si < HH) & (sj >= 0) & (sj < WW);

        f32x4 v = (f32x4)(0.f);
        if (valid) {
            long long src = base_b + (long long)(((si * WW + sj) * 8 + dd) * 4 + f4);
            v = in[src];
        }
        long long dst = base_b + (long long)(((h * WW + w) * 8 + d) * 4 + f4);
        __builtin_nontemporal_store(v, &out[dst]);
    }
}

extern "C" void kernel_launch(void* const* d_in, const int* in_sizes, int n_in,
                              void* d_out, int out_size, void* d_ws, size_t ws_size,
                              hipStream_t stream) {
    const f32x4* in = (const f32x4*)d_in[0];
    f32x4* out = (f32x4*)d_out;
    aug_tiled<<<256, 1024, 0, stream>>>(in, out);
}